// Round 1
// baseline (510.435 us; speedup 1.0000x reference)
//
#include <hip/hip_runtime.h>
#include <hip/hip_bf16.h>
#include <math.h>

#define Hdim 128
#define NBq 8
#define SIq 16

// ---------------- gather: X0 = embedding[node_ids] ----------------
__global__ void k_gather(const float* __restrict__ emb, const int* __restrict__ ids,
                         float* __restrict__ x0, int N) {
  int idx = blockIdx.x * blockDim.x + threadIdx.x;   // one float4 per thread
  int total = N * (Hdim / 4);
  if (idx >= total) return;
  int n  = idx / (Hdim / 4);
  int c4 = idx - n * (Hdim / 4);
  int s  = ids[n];
  ((float4*)x0)[(size_t)n * (Hdim / 4) + c4] =
      ((const float4*)emb)[(size_t)s * (Hdim / 4) + c4];
}

// ---------------- edge messages: agg[dst] += bdd(h[src], W[etype]) * norm ----------------
// 256 threads = 2 edges x 128 features; 4 iterations -> 8 edges per block.
__global__ __launch_bounds__(256) void k_edge(
    const float* __restrict__ h, const float* __restrict__ W,
    const int* __restrict__ src, const int* __restrict__ dst,
    const int* __restrict__ et, const float* __restrict__ norm,
    float* __restrict__ agg, int E) {
  __shared__ float xs[2][Hdim];
  int t  = threadIdx.x;
  int el = t >> 7;          // 0/1: which edge of the pair
  int f  = t & 127;         // feature
  int b  = f >> 4, o = f & 15;
  int base = blockIdx.x * 8;
  for (int it = 0; it < 4; ++it) {
    int e = base + it * 2 + el;
    __syncthreads();        // protect previous iteration's xs reads
    int d = 0, r = 0; float nv = 0.f;
    if (e < E) {
      int s = src[e];
      d = dst[e]; r = et[e]; nv = norm[e];
      xs[el][f] = h[(size_t)s * Hdim + f];
    }
    __syncthreads();
    if (e < E) {
      const float* wp = W + ((size_t)r * NBq + b) * (SIq * SIq) + o;
      const float* xp = &xs[el][b * SIq];
      float acc = 0.f;
#pragma unroll
      for (int i = 0; i < SIq; ++i) acc += xp[i] * wp[i * SIq];
      atomicAdd(&agg[(size_t)d * Hdim + f], acc * nv);
    }
  }
}

// ---------------- GEMM: C[M,Nc] = A[M,128] @ B[128,Nc] (+addm)(+bias)(+addm2)(relu) ----------------
// BM=64, BN=64, BK=16, 256 threads, 4x4 per thread.
__global__ __launch_bounds__(256) void k_gemm(
    const float* __restrict__ A, const float* __restrict__ B, float* __restrict__ C,
    const float* __restrict__ addm, const float* __restrict__ bias,
    const float* __restrict__ addm2, int M, int Nc, int relu) {
  __shared__ float As[16][68];   // [k][m], row stride 68 floats = 272B (16B aligned)
  __shared__ float Bs[16][64];   // [k][n]
  int t  = threadIdx.x;
  int tx = t & 15, ty = t >> 4;
  int bm = blockIdx.x * 64, bn = blockIdx.y * 64;
  int ar = t >> 2, akq = (t & 3) << 2;   // A load: row, k-quad
  int bk = t >> 4, bc = (t & 15) << 2;   // B load: k-row, col-quad
  float acc[4][4] = {};
  for (int k0 = 0; k0 < Hdim; k0 += 16) {
    float4 av = *(const float4*)(A + (size_t)(bm + ar) * Hdim + k0 + akq);
    float4 bv = *(const float4*)(B + (size_t)(k0 + bk) * Nc + bn + bc);
    __syncthreads();
    As[akq + 0][ar] = av.x; As[akq + 1][ar] = av.y;
    As[akq + 2][ar] = av.z; As[akq + 3][ar] = av.w;
    *(float4*)&Bs[bk][bc] = bv;
    __syncthreads();
#pragma unroll
    for (int kk = 0; kk < 16; ++kk) {
      float4 a = *(const float4*)&As[kk][ty << 2];
      float4 bb = *(const float4*)&Bs[kk][tx << 2];
      acc[0][0] += a.x * bb.x; acc[0][1] += a.x * bb.y; acc[0][2] += a.x * bb.z; acc[0][3] += a.x * bb.w;
      acc[1][0] += a.y * bb.x; acc[1][1] += a.y * bb.y; acc[1][2] += a.y * bb.z; acc[1][3] += a.y * bb.w;
      acc[2][0] += a.z * bb.x; acc[2][1] += a.z * bb.y; acc[2][2] += a.z * bb.z; acc[2][3] += a.z * bb.w;
      acc[3][0] += a.w * bb.x; acc[3][1] += a.w * bb.y; acc[3][2] += a.w * bb.z; acc[3][3] += a.w * bb.w;
    }
  }
  int col = bn + (tx << 2);
  float4 bvv = {0.f, 0.f, 0.f, 0.f};
  if (bias) bvv = *(const float4*)(bias + col);
#pragma unroll
  for (int r = 0; r < 4; ++r) {
    int row = bm + (ty << 2) + r;
    size_t off = (size_t)row * Nc + col;
    float4 v;
    v.x = acc[r][0] + bvv.x; v.y = acc[r][1] + bvv.y;
    v.z = acc[r][2] + bvv.z; v.w = acc[r][3] + bvv.w;
    if (addm)  { float4 m = *(const float4*)(addm + off);  v.x += m.x; v.y += m.y; v.z += m.z; v.w += m.w; }
    if (addm2) { float4 m = *(const float4*)(addm2 + off); v.x += m.x; v.y += m.y; v.z += m.z; v.w += m.w; }
    if (relu) {
      v.x = fmaxf(v.x, 0.f); v.y = fmaxf(v.y, 0.f);
      v.z = fmaxf(v.z, 0.f); v.w = fmaxf(v.w, 0.f);
    }
    *(float4*)(C + off) = v;
  }
}

// ---------------- z = zml[:, :128] + exp(zml[:, 128:]) * eps ----------------
__global__ void k_z(const float* __restrict__ zml, const float* __restrict__ eps,
                    float* __restrict__ z, int N) {
  int idx = blockIdx.x * blockDim.x + threadIdx.x;
  if (idx >= N * Hdim) return;
  int n = idx >> 7, j = idx & 127;
  float mean = zml[(size_t)n * 256 + j];
  float ls   = zml[(size_t)n * 256 + 128 + j];
  z[idx] = mean + expf(ls) * eps[idx];
}

// ---------------- G[128,128] += X^T @ Y  (split-K over grid, atomics) ----------------
__global__ __launch_bounds__(256) void k_xty(const float* __restrict__ X,
                                             const float* __restrict__ Y,
                                             float* __restrict__ G, int N) {
  __shared__ float xs[8][Hdim];
  __shared__ float ys[8][Hdim];
  int t  = threadIdx.x;
  int tx = t & 15, ty = t >> 4;
  int KC = N / gridDim.x;
  int k0 = blockIdx.x * KC;
  int lr = t >> 5, lc = (t & 31) << 2;
  float acc[8][8] = {};
  for (int kb = 0; kb < KC; kb += 8) {
    __syncthreads();
    *(float4*)&xs[lr][lc] = *(const float4*)(X + (size_t)(k0 + kb + lr) * Hdim + lc);
    *(float4*)&ys[lr][lc] = *(const float4*)(Y + (size_t)(k0 + kb + lr) * Hdim + lc);
    __syncthreads();
#pragma unroll
    for (int kk = 0; kk < 8; ++kk) {
      float xv[8], yv[8];
      *(float4*)&xv[0] = *(const float4*)&xs[kk][ty * 8];
      *(float4*)&xv[4] = *(const float4*)&xs[kk][ty * 8 + 4];
      *(float4*)&yv[0] = *(const float4*)&ys[kk][tx * 8];
      *(float4*)&yv[4] = *(const float4*)&ys[kk][tx * 8 + 4];
#pragma unroll
      for (int r = 0; r < 8; ++r)
#pragma unroll
        for (int c = 0; c < 8; ++c) acc[r][c] += xv[r] * yv[c];
    }
  }
#pragma unroll
  for (int r = 0; r < 8; ++r)
#pragma unroll
    for (int c = 0; c < 8; ++c)
      atomicAdd(&G[(size_t)(ty * 8 + r) * Hdim + tx * 8 + c], acc[r][c]);
}

extern "C" void kernel_launch(void* const* d_in, const int* in_sizes, int n_in,
                              void* d_out, int out_size, void* d_ws, size_t ws_size,
                              hipStream_t stream) {
  const int*   node_ids = (const int*)d_in[0];
  const int*   src      = (const int*)d_in[1];
  const int*   dst      = (const int*)d_in[2];
  const int*   et       = (const int*)d_in[3];
  const float* norm     = (const float*)d_in[4];
  const float* eps      = (const float*)d_in[5];
  const float* emb      = (const float*)d_in[6];
  const float* W0       = (const float*)d_in[7];
  const float* loop0    = (const float*)d_in[8];
  const float* b0       = (const float*)d_in[9];
  const float* W1       = (const float*)d_in[10];
  const float* loop1    = (const float*)d_in[11];
  const float* b1       = (const float*)d_in[12];
  const float* Wz       = (const float*)d_in[13];
  const float* bz       = (const float*)d_in[14];
  const float* Wi       = (const float*)d_in[15];
  const float* bi       = (const float*)d_in[16];
  const float* hbi      = (const float*)d_in[17];
  const float* Wo       = (const float*)d_in[18];
  const float* bo       = (const float*)d_in[19];
  const float* hbo      = (const float*)d_in[20];
  float* out = (float*)d_out;

  const int N = in_sizes[0];   // 8192
  const int E = in_sizes[1];   // 131072

  char* ws = (char*)d_ws;
  const size_t MB = 1u << 20;
  float* X0  = (float*)(ws + 0 * MB);
  float* B1p = (float*)(ws + 4 * MB);
  float* B2p = (float*)(ws + 8 * MB);
  float* AGG = (float*)(ws + 12 * MB);
  float* B3p = (float*)(ws + 16 * MB);
  float* ZML = (float*)(ws + 12 * MB);   // overlaps AGG+B3 (both dead during its lifetime)
  float* G   = (float*)(ws + 20 * MB);

  dim3 blk(256);
  size_t nhBytes = (size_t)N * Hdim * sizeof(float);

  // 1. x0
  k_gather<<<dim3((N * (Hdim / 4) + 255) / 256), blk, 0, stream>>>(emb, node_ids, X0, N);
  // 2. layer-0 edge aggregation
  hipMemsetAsync(AGG, 0, nhBytes, stream);
  k_edge<<<dim3((E + 7) / 8), blk, 0, stream>>>(X0, W0, src, dst, et, norm, AGG, E);
  // 3. h1 = relu(agg + b0 + x0@loop0)
  k_gemm<<<dim3(N / 64, Hdim / 64), blk, 0, stream>>>(X0, loop0, B1p, AGG, b0, nullptr, N, Hdim, 1);
  // 4. layer-1 edge aggregation
  hipMemsetAsync(AGG, 0, nhBytes, stream);
  k_edge<<<dim3((E + 7) / 8), blk, 0, stream>>>(B1p, W1, src, dst, et, norm, AGG, E);
  // 5. h2 = agg + b1 + h1@loop1
  k_gemm<<<dim3(N / 64, Hdim / 64), blk, 0, stream>>>(B1p, loop1, B2p, AGG, b1, nullptr, N, Hdim, 0);
  // 6. zml = h2@Wz + bz   [N, 256]
  k_gemm<<<dim3(N / 64, 256 / 64), blk, 0, stream>>>(B2p, Wz, ZML, nullptr, bz, nullptr, N, 256, 0);
  // 7. z = mean + exp(log_std)*eps  -> B1p
  k_z<<<dim3((N * Hdim) / 256), blk, 0, stream>>>(ZML, eps, B1p, N);
  // 8. C1 = z@Wi + bi + x0 -> B3p
  k_gemm<<<dim3(N / 64, Hdim / 64), blk, 0, stream>>>(B1p, Wi, B3p, nullptr, bi, X0, N, Hdim, 0);
  // 9. G1 = z^T @ C1
  hipMemsetAsync(G, 0, (size_t)Hdim * Hdim * sizeof(float), stream);
  k_xty<<<dim3(128), blk, 0, stream>>>(B1p, B3p, G, N);
  // 10. h3 = z@G1 + hbi -> B2p
  k_gemm<<<dim3(N / 64, Hdim / 64), blk, 0, stream>>>(B1p, G, B2p, nullptr, hbi, nullptr, N, Hdim, 0);
  // 11. C2 = h3@Wo + bo + x0 -> B3p
  k_gemm<<<dim3(N / 64, Hdim / 64), blk, 0, stream>>>(B2p, Wo, B3p, nullptr, bo, X0, N, Hdim, 0);
  // 12. G2 = h3^T @ C2
  hipMemsetAsync(G, 0, (size_t)Hdim * Hdim * sizeof(float), stream);
  k_xty<<<dim3(128), blk, 0, stream>>>(B2p, B3p, G, N);
  // 13. out = h3@G2 + hbo
  k_gemm<<<dim3(N / 64, Hdim / 64), blk, 0, stream>>>(B2p, G, out, nullptr, hbo, nullptr, N, Hdim, 0);
}

// Round 2
// 381.831 us; speedup vs baseline: 1.3368x; 1.3368x over previous
//
#include <hip/hip_runtime.h>
#include <hip/hip_bf16.h>
#include <math.h>

#define Hdim 128
#define NBq 8
#define SIq 16

// ---------------- gather: X0 = embedding[node_ids] ----------------
__global__ void k_gather(const float* __restrict__ emb, const int* __restrict__ ids,
                         float* __restrict__ x0, int N) {
  int idx = blockIdx.x * blockDim.x + threadIdx.x;   // one float4 per thread
  int total = N * (Hdim / 4);
  if (idx >= total) return;
  int n  = idx / (Hdim / 4);
  int c4 = idx - n * (Hdim / 4);
  int s  = ids[n];
  ((float4*)x0)[(size_t)n * (Hdim / 4) + c4] =
      ((const float4*)emb)[(size_t)s * (Hdim / 4) + c4];
}

// ---------------- edge messages: agg[dst] += bdd(h[src], W[etype]) * norm ----------------
// 256 threads = 2 edges x 128 features; 4 iterations -> 8 edges per block.
__global__ __launch_bounds__(256) void k_edge(
    const float* __restrict__ h, const float* __restrict__ W,
    const int* __restrict__ src, const int* __restrict__ dst,
    const int* __restrict__ et, const float* __restrict__ norm,
    float* __restrict__ agg, int E) {
  __shared__ float xs[2][Hdim];
  int t  = threadIdx.x;
  int el = t >> 7;          // 0/1: which edge of the pair
  int f  = t & 127;         // feature
  int b  = f >> 4, o = f & 15;
  int base = blockIdx.x * 8;
  for (int it = 0; it < 4; ++it) {
    int e = base + it * 2 + el;
    __syncthreads();        // protect previous iteration's xs reads
    int d = 0, r = 0; float nv = 0.f;
    if (e < E) {
      int s = src[e];
      d = dst[e]; r = et[e]; nv = norm[e];
      xs[el][f] = h[(size_t)s * Hdim + f];
    }
    __syncthreads();
    if (e < E) {
      const float* wp = W + ((size_t)r * NBq + b) * (SIq * SIq) + o;
      const float* xp = &xs[el][b * SIq];
      float acc = 0.f;
#pragma unroll
      for (int i = 0; i < SIq; ++i) acc += xp[i] * wp[i * SIq];
      atomicAdd(&agg[(size_t)d * Hdim + f], acc * nv);
    }
  }
}

// ---------------- GEMM: C[M,Nc] = A[M,128] @ B[128,Nc] (+addm)(+bias)(+addm2)(relu) ----------------
// BM=64, BN=64, BK=16, 256 threads, 4x4 per thread.
__global__ __launch_bounds__(256) void k_gemm(
    const float* __restrict__ A, const float* __restrict__ B, float* __restrict__ C,
    const float* __restrict__ addm, const float* __restrict__ bias,
    const float* __restrict__ addm2, int M, int Nc, int relu) {
  __shared__ float As[16][68];   // [k][m], row stride 68 floats = 272B (16B aligned)
  __shared__ float Bs[16][64];   // [k][n]
  int t  = threadIdx.x;
  int tx = t & 15, ty = t >> 4;
  int bm = blockIdx.x * 64, bn = blockIdx.y * 64;
  int ar = t >> 2, akq = (t & 3) << 2;   // A load: row, k-quad
  int bk = t >> 4, bc = (t & 15) << 2;   // B load: k-row, col-quad
  float acc[4][4] = {};
  for (int k0 = 0; k0 < Hdim; k0 += 16) {
    float4 av = *(const float4*)(A + (size_t)(bm + ar) * Hdim + k0 + akq);
    float4 bv = *(const float4*)(B + (size_t)(k0 + bk) * Nc + bn + bc);
    __syncthreads();
    As[akq + 0][ar] = av.x; As[akq + 1][ar] = av.y;
    As[akq + 2][ar] = av.z; As[akq + 3][ar] = av.w;
    *(float4*)&Bs[bk][bc] = bv;
    __syncthreads();
#pragma unroll
    for (int kk = 0; kk < 16; ++kk) {
      float4 a = *(const float4*)&As[kk][ty << 2];
      float4 bb = *(const float4*)&Bs[kk][tx << 2];
      acc[0][0] += a.x * bb.x; acc[0][1] += a.x * bb.y; acc[0][2] += a.x * bb.z; acc[0][3] += a.x * bb.w;
      acc[1][0] += a.y * bb.x; acc[1][1] += a.y * bb.y; acc[1][2] += a.y * bb.z; acc[1][3] += a.y * bb.w;
      acc[2][0] += a.z * bb.x; acc[2][1] += a.z * bb.y; acc[2][2] += a.z * bb.z; acc[2][3] += a.z * bb.w;
      acc[3][0] += a.w * bb.x; acc[3][1] += a.w * bb.y; acc[3][2] += a.w * bb.z; acc[3][3] += a.w * bb.w;
    }
  }
  int col = bn + (tx << 2);
  float4 bvv = {0.f, 0.f, 0.f, 0.f};
  if (bias) bvv = *(const float4*)(bias + col);
#pragma unroll
  for (int r = 0; r < 4; ++r) {
    int row = bm + (ty << 2) + r;
    size_t off = (size_t)row * Nc + col;
    float4 v;
    v.x = acc[r][0] + bvv.x; v.y = acc[r][1] + bvv.y;
    v.z = acc[r][2] + bvv.z; v.w = acc[r][3] + bvv.w;
    if (addm)  { float4 m = *(const float4*)(addm + off);  v.x += m.x; v.y += m.y; v.z += m.z; v.w += m.w; }
    if (addm2) { float4 m = *(const float4*)(addm2 + off); v.x += m.x; v.y += m.y; v.z += m.z; v.w += m.w; }
    if (relu) {
      v.x = fmaxf(v.x, 0.f); v.y = fmaxf(v.y, 0.f);
      v.z = fmaxf(v.z, 0.f); v.w = fmaxf(v.w, 0.f);
    }
    *(float4*)(C + off) = v;
  }
}

// ---------------- z = zml[:, :128] + exp(zml[:, 128:]) * eps ----------------
__global__ void k_z(const float* __restrict__ zml, const float* __restrict__ eps,
                    float* __restrict__ z, int N) {
  int idx = blockIdx.x * blockDim.x + threadIdx.x;
  if (idx >= N * Hdim) return;
  int n = idx >> 7, j = idx & 127;
  float mean = zml[(size_t)n * 256 + j];
  float ls   = zml[(size_t)n * 256 + 128 + j];
  z[idx] = mean + expf(ls) * eps[idx];
}

// ---------------- G[128,128] += X^T @ Y  (split-K over grid, atomics) ----------------
// Each block: one 64x64 quadrant of G over a K-slice. 256 threads, 4x4/thread
// (16 accumulators -> no VGPR spill; the old 8x8 tile spilled: VGPR=52 with
// 64 accs, 67 MB scratch WRITE_SIZE, 100 us).
__global__ __launch_bounds__(256) void k_xty(const float* __restrict__ X,
                                             const float* __restrict__ Y,
                                             float* __restrict__ G, int N) {
  __shared__ float xs[8][64];
  __shared__ float ys[8][64];
  int t  = threadIdx.x;
  int tx = t & 15, ty = t >> 4;       // 16x16 threads
  int qr = blockIdx.y >> 1, qc = blockIdx.y & 1;
  int KC = N / gridDim.x;             // rows per K-slice
  int k0 = blockIdx.x * KC;
  // cooperative load mapping: t<128 loads xs, t>=128 loads ys (one float4 each)
  int m  = t >> 7, li = t & 127;
  int lr = li >> 4, lc = (li & 15) << 2;
  const float* S = m ? Y : X;
  int coff = (m ? qc : qr) * 64;
  float acc[4][4] = {};
  for (int kb = 0; kb < KC; kb += 8) {
    float4 v = *(const float4*)(S + (size_t)(k0 + kb + lr) * Hdim + coff + lc);
    __syncthreads();
    if (m) *(float4*)&ys[lr][lc] = v; else *(float4*)&xs[lr][lc] = v;
    __syncthreads();
#pragma unroll
    for (int kk = 0; kk < 8; ++kk) {
      float4 xv = *(const float4*)&xs[kk][ty << 2];
      float4 yv = *(const float4*)&ys[kk][tx << 2];
      acc[0][0] += xv.x * yv.x; acc[0][1] += xv.x * yv.y; acc[0][2] += xv.x * yv.z; acc[0][3] += xv.x * yv.w;
      acc[1][0] += xv.y * yv.x; acc[1][1] += xv.y * yv.y; acc[1][2] += xv.y * yv.z; acc[1][3] += xv.y * yv.w;
      acc[2][0] += xv.z * yv.x; acc[2][1] += xv.z * yv.y; acc[2][2] += xv.z * yv.z; acc[2][3] += xv.z * yv.w;
      acc[3][0] += xv.w * yv.x; acc[3][1] += xv.w * yv.y; acc[3][2] += xv.w * yv.z; acc[3][3] += xv.w * yv.w;
    }
  }
  int grow = qr * 64 + (ty << 2);
  int gcol = qc * 64 + (tx << 2);
#pragma unroll
  for (int r = 0; r < 4; ++r)
#pragma unroll
    for (int c = 0; c < 4; ++c)
      atomicAdd(&G[(size_t)(grow + r) * Hdim + gcol + c], acc[r][c]);
}

extern "C" void kernel_launch(void* const* d_in, const int* in_sizes, int n_in,
                              void* d_out, int out_size, void* d_ws, size_t ws_size,
                              hipStream_t stream) {
  const int*   node_ids = (const int*)d_in[0];
  const int*   src      = (const int*)d_in[1];
  const int*   dst      = (const int*)d_in[2];
  const int*   et       = (const int*)d_in[3];
  const float* norm     = (const float*)d_in[4];
  const float* eps      = (const float*)d_in[5];
  const float* emb      = (const float*)d_in[6];
  const float* W0       = (const float*)d_in[7];
  const float* loop0    = (const float*)d_in[8];
  const float* b0       = (const float*)d_in[9];
  const float* W1       = (const float*)d_in[10];
  const float* loop1    = (const float*)d_in[11];
  const float* b1       = (const float*)d_in[12];
  const float* Wz       = (const float*)d_in[13];
  const float* bz       = (const float*)d_in[14];
  const float* Wi       = (const float*)d_in[15];
  const float* bi       = (const float*)d_in[16];
  const float* hbi      = (const float*)d_in[17];
  const float* Wo       = (const float*)d_in[18];
  const float* bo       = (const float*)d_in[19];
  const float* hbo      = (const float*)d_in[20];
  float* out = (float*)d_out;

  const int N = in_sizes[0];   // 8192
  const int E = in_sizes[1];   // 131072

  char* ws = (char*)d_ws;
  const size_t MB = 1u << 20;
  float* X0  = (float*)(ws + 0 * MB);
  float* B1p = (float*)(ws + 4 * MB);
  float* B2p = (float*)(ws + 8 * MB);
  float* AGG = (float*)(ws + 12 * MB);
  float* B3p = (float*)(ws + 16 * MB);
  float* ZML = (float*)(ws + 12 * MB);   // overlaps AGG+B3 (both dead during its lifetime)
  float* G   = (float*)(ws + 20 * MB);

  dim3 blk(256);
  size_t nhBytes = (size_t)N * Hdim * sizeof(float);

  // 1. x0
  k_gather<<<dim3((N * (Hdim / 4) + 255) / 256), blk, 0, stream>>>(emb, node_ids, X0, N);
  // 2. layer-0 edge aggregation
  hipMemsetAsync(AGG, 0, nhBytes, stream);
  k_edge<<<dim3((E + 7) / 8), blk, 0, stream>>>(X0, W0, src, dst, et, norm, AGG, E);
  // 3. h1 = relu(agg + b0 + x0@loop0)
  k_gemm<<<dim3(N / 64, Hdim / 64), blk, 0, stream>>>(X0, loop0, B1p, AGG, b0, nullptr, N, Hdim, 1);
  // 4. layer-1 edge aggregation
  hipMemsetAsync(AGG, 0, nhBytes, stream);
  k_edge<<<dim3((E + 7) / 8), blk, 0, stream>>>(B1p, W1, src, dst, et, norm, AGG, E);
  // 5. h2 = agg + b1 + h1@loop1
  k_gemm<<<dim3(N / 64, Hdim / 64), blk, 0, stream>>>(B1p, loop1, B2p, AGG, b1, nullptr, N, Hdim, 0);
  // 6. zml = h2@Wz + bz   [N, 256]
  k_gemm<<<dim3(N / 64, 256 / 64), blk, 0, stream>>>(B2p, Wz, ZML, nullptr, bz, nullptr, N, 256, 0);
  // 7. z = mean + exp(log_std)*eps  -> B1p
  k_z<<<dim3((N * Hdim) / 256), blk, 0, stream>>>(ZML, eps, B1p, N);
  // 8. C1 = z@Wi + bi + x0 -> B3p
  k_gemm<<<dim3(N / 64, Hdim / 64), blk, 0, stream>>>(B1p, Wi, B3p, nullptr, bi, X0, N, Hdim, 0);
  // 9. G1 = z^T @ C1
  hipMemsetAsync(G, 0, (size_t)Hdim * Hdim * sizeof(float), stream);
  k_xty<<<dim3(32, 4), blk, 0, stream>>>(B1p, B3p, G, N);
  // 10. h3 = z@G1 + hbi -> B2p
  k_gemm<<<dim3(N / 64, Hdim / 64), blk, 0, stream>>>(B1p, G, B2p, nullptr, hbi, nullptr, N, Hdim, 0);
  // 11. C2 = h3@Wo + bo + x0 -> B3p
  k_gemm<<<dim3(N / 64, Hdim / 64), blk, 0, stream>>>(B2p, Wo, B3p, nullptr, bo, X0, N, Hdim, 0);
  // 12. G2 = h3^T @ C2
  hipMemsetAsync(G, 0, (size_t)Hdim * Hdim * sizeof(float), stream);
  k_xty<<<dim3(32, 4), blk, 0, stream>>>(B2p, B3p, G, N);
  // 13. out = h3@G2 + hbo
  k_gemm<<<dim3(N / 64, Hdim / 64), blk, 0, stream>>>(B2p, G, out, nullptr, hbo, nullptr, N, Hdim, 0);
}

// Round 3
// 365.220 us; speedup vs baseline: 1.3976x; 1.0455x over previous
//
#include <hip/hip_runtime.h>
#include <hip/hip_bf16.h>
#include <math.h>

#define Hdim 128
#define NBq 8
#define SIq 16

// ---------------- gather: X0 = embedding[node_ids] ----------------
__global__ void k_gather(const float* __restrict__ emb, const int* __restrict__ ids,
                         float* __restrict__ x0, int N) {
  int idx = blockIdx.x * blockDim.x + threadIdx.x;   // one float4 per thread
  int total = N * (Hdim / 4);
  if (idx >= total) return;
  int n  = idx / (Hdim / 4);
  int c4 = idx - n * (Hdim / 4);
  int s  = ids[n];
  ((float4*)x0)[(size_t)n * (Hdim / 4) + c4] =
      ((const float4*)emb)[(size_t)s * (Hdim / 4) + c4];
}

// ---------------- CSR build: histogram / scan / scatter-permute ----------------
__global__ void k_hist(const int* __restrict__ dst, int* __restrict__ cnt, int E) {
  int e = blockIdx.x * blockDim.x + threadIdx.x;
  if (e < E) atomicAdd(&cnt[dst[e]], 1);
}

// single block, 1024 threads, N multiple of 1024
__global__ __launch_bounds__(1024) void k_scan(const int* __restrict__ cnt,
                                               int* __restrict__ off,
                                               int* __restrict__ cur, int N, int E) {
  __shared__ int part[1024];
  int t = threadIdx.x;
  int ipt = N / 1024;            // items per thread (8)
  int base = t * ipt;
  int loc[8];
  int s = 0;
  for (int i = 0; i < ipt; ++i) { loc[i] = s; s += cnt[base + i]; }
  part[t] = s;
  __syncthreads();
  for (int d = 1; d < 1024; d <<= 1) {
    int v = part[t];
    int add = (t >= d) ? part[t - d] : 0;
    __syncthreads();
    part[t] = v + add;
    __syncthreads();
  }
  int pre = (t == 0) ? 0 : part[t - 1];
  for (int i = 0; i < ipt; ++i) {
    int o = pre + loc[i];
    off[base + i] = o;
    cur[base + i] = o;
  }
  if (t == 0) off[N] = E;
}

__global__ void k_scatter(const int* __restrict__ src, const int* __restrict__ dst,
                          const int* __restrict__ et, const float* __restrict__ norm,
                          int* __restrict__ cur, int* __restrict__ psrc,
                          int* __restrict__ pet, float* __restrict__ pnorm, int E) {
  int e = blockIdx.x * blockDim.x + threadIdx.x;
  if (e >= E) return;
  int p = atomicAdd(&cur[dst[e]], 1);
  psrc[p] = src[e];
  pet[p]  = et[e];
  pnorm[p] = norm[e];
}

// ---------------- segment-reduce edge aggregation (no atomics) ----------------
// one block (128 threads) per destination node; 4 edges per sync round.
__global__ __launch_bounds__(128) void k_edge2(
    const float* __restrict__ h, const float* __restrict__ W,
    const int* __restrict__ off, const int* __restrict__ psrc,
    const int* __restrict__ pet, const float* __restrict__ pnorm,
    float* __restrict__ agg) {
  int n = blockIdx.x;
  int f = threadIdx.x;          // feature 0..127
  int b = f >> 4, o = f & 15;
  int j0 = off[n], j1 = off[n + 1];
  __shared__ float xs[4][Hdim];
  float acc = 0.f;
  for (int j = j0; j < j1; j += 4) {
    int m = min(4, j1 - j);
    for (int q = 0; q < m; ++q)
      xs[q][f] = h[(size_t)psrc[j + q] * Hdim + f];
    __syncthreads();
    for (int q = 0; q < m; ++q) {
      int r = pet[j + q];
      float nv = pnorm[j + q];
      const float* wp = W + ((size_t)r * NBq + b) * (SIq * SIq) + o;
      const float* xp = &xs[q][b * SIq];
      float a = 0.f;
#pragma unroll
      for (int i = 0; i < SIq; ++i) a += xp[i] * wp[i * SIq];
      acc += a * nv;
    }
    __syncthreads();
  }
  agg[(size_t)n * Hdim + f] = acc;
}

// ---------------- GEMM: C[M,Nc] = A[M,128] @ B[128,Nc] (+addm)(+bias)(+addm2)(relu) ----------------
// BM=64, BN=64, BK=16, 256 threads, 4x4 per thread.
__global__ __launch_bounds__(256) void k_gemm(
    const float* __restrict__ A, const float* __restrict__ B, float* __restrict__ C,
    const float* __restrict__ addm, const float* __restrict__ bias,
    const float* __restrict__ addm2, int M, int Nc, int relu) {
  __shared__ float As[16][68];
  __shared__ float Bs[16][64];
  int t  = threadIdx.x;
  int tx = t & 15, ty = t >> 4;
  int bm = blockIdx.x * 64, bn = blockIdx.y * 64;
  int ar = t >> 2, akq = (t & 3) << 2;
  int bk = t >> 4, bc = (t & 15) << 2;
  float acc[4][4] = {};
  for (int k0 = 0; k0 < Hdim; k0 += 16) {
    float4 av = *(const float4*)(A + (size_t)(bm + ar) * Hdim + k0 + akq);
    float4 bv = *(const float4*)(B + (size_t)(k0 + bk) * Nc + bn + bc);
    __syncthreads();
    As[akq + 0][ar] = av.x; As[akq + 1][ar] = av.y;
    As[akq + 2][ar] = av.z; As[akq + 3][ar] = av.w;
    *(float4*)&Bs[bk][bc] = bv;
    __syncthreads();
#pragma unroll
    for (int kk = 0; kk < 16; ++kk) {
      float4 a = *(const float4*)&As[kk][ty << 2];
      float4 bb = *(const float4*)&Bs[kk][tx << 2];
      acc[0][0] += a.x * bb.x; acc[0][1] += a.x * bb.y; acc[0][2] += a.x * bb.z; acc[0][3] += a.x * bb.w;
      acc[1][0] += a.y * bb.x; acc[1][1] += a.y * bb.y; acc[1][2] += a.y * bb.z; acc[1][3] += a.y * bb.w;
      acc[2][0] += a.z * bb.x; acc[2][1] += a.z * bb.y; acc[2][2] += a.z * bb.z; acc[2][3] += a.z * bb.w;
      acc[3][0] += a.w * bb.x; acc[3][1] += a.w * bb.y; acc[3][2] += a.w * bb.z; acc[3][3] += a.w * bb.w;
    }
  }
  int col = bn + (tx << 2);
  float4 bvv = {0.f, 0.f, 0.f, 0.f};
  if (bias) bvv = *(const float4*)(bias + col);
#pragma unroll
  for (int r = 0; r < 4; ++r) {
    int row = bm + (ty << 2) + r;
    size_t off = (size_t)row * Nc + col;
    float4 v;
    v.x = acc[r][0] + bvv.x; v.y = acc[r][1] + bvv.y;
    v.z = acc[r][2] + bvv.z; v.w = acc[r][3] + bvv.w;
    if (addm)  { float4 m = *(const float4*)(addm + off);  v.x += m.x; v.y += m.y; v.z += m.z; v.w += m.w; }
    if (addm2) { float4 m = *(const float4*)(addm2 + off); v.x += m.x; v.y += m.y; v.z += m.z; v.w += m.w; }
    if (relu) {
      v.x = fmaxf(v.x, 0.f); v.y = fmaxf(v.y, 0.f);
      v.z = fmaxf(v.z, 0.f); v.w = fmaxf(v.w, 0.f);
    }
    *(float4*)(C + off) = v;
  }
}

// ---------------- z = zml[:, :128] + exp(zml[:, 128:]) * eps ----------------
__global__ void k_z(const float* __restrict__ zml, const float* __restrict__ eps,
                    float* __restrict__ z, int N) {
  int idx = blockIdx.x * blockDim.x + threadIdx.x;
  if (idx >= N * Hdim) return;
  int n = idx >> 7, j = idx & 127;
  float mean = zml[(size_t)n * 256 + j];
  float ls   = zml[(size_t)n * 256 + 128 + j];
  z[idx] = mean + expf(ls) * eps[idx];
}

// ---------------- G[128,128] += X^T @ Y  (split-K, 4x4/thread, no spill) ----------------
__global__ __launch_bounds__(256) void k_xty(const float* __restrict__ X,
                                             const float* __restrict__ Y,
                                             float* __restrict__ G, int N) {
  __shared__ float xs[8][64];
  __shared__ float ys[8][64];
  int t  = threadIdx.x;
  int tx = t & 15, ty = t >> 4;
  int qr = blockIdx.y >> 1, qc = blockIdx.y & 1;
  int KC = N / gridDim.x;
  int k0 = blockIdx.x * KC;
  int m  = t >> 7, li = t & 127;
  int lr = li >> 4, lc = (li & 15) << 2;
  const float* S = m ? Y : X;
  int coff = (m ? qc : qr) * 64;
  float acc[4][4] = {};
  for (int kb = 0; kb < KC; kb += 8) {
    float4 v = *(const float4*)(S + (size_t)(k0 + kb + lr) * Hdim + coff + lc);
    __syncthreads();
    if (m) *(float4*)&ys[lr][lc] = v; else *(float4*)&xs[lr][lc] = v;
    __syncthreads();
#pragma unroll
    for (int kk = 0; kk < 8; ++kk) {
      float4 xv = *(const float4*)&xs[kk][ty << 2];
      float4 yv = *(const float4*)&ys[kk][tx << 2];
      acc[0][0] += xv.x * yv.x; acc[0][1] += xv.x * yv.y; acc[0][2] += xv.x * yv.z; acc[0][3] += xv.x * yv.w;
      acc[1][0] += xv.y * yv.x; acc[1][1] += xv.y * yv.y; acc[1][2] += xv.y * yv.z; acc[1][3] += xv.y * yv.w;
      acc[2][0] += xv.z * yv.x; acc[2][1] += xv.z * yv.y; acc[2][2] += xv.z * yv.z; acc[2][3] += xv.z * yv.w;
      acc[3][0] += xv.w * yv.x; acc[3][1] += xv.w * yv.y; acc[3][2] += xv.w * yv.z; acc[3][3] += xv.w * yv.w;
    }
  }
  int grow = qr * 64 + (ty << 2);
  int gcol = qc * 64 + (tx << 2);
#pragma unroll
  for (int r = 0; r < 4; ++r)
#pragma unroll
    for (int c = 0; c < 4; ++c)
      atomicAdd(&G[(size_t)(grow + r) * Hdim + gcol + c], acc[r][c]);
}

extern "C" void kernel_launch(void* const* d_in, const int* in_sizes, int n_in,
                              void* d_out, int out_size, void* d_ws, size_t ws_size,
                              hipStream_t stream) {
  const int*   node_ids = (const int*)d_in[0];
  const int*   src      = (const int*)d_in[1];
  const int*   dst      = (const int*)d_in[2];
  const int*   et       = (const int*)d_in[3];
  const float* norm     = (const float*)d_in[4];
  const float* eps      = (const float*)d_in[5];
  const float* emb      = (const float*)d_in[6];
  const float* W0       = (const float*)d_in[7];
  const float* loop0    = (const float*)d_in[8];
  const float* b0       = (const float*)d_in[9];
  const float* W1       = (const float*)d_in[10];
  const float* loop1    = (const float*)d_in[11];
  const float* b1       = (const float*)d_in[12];
  const float* Wz       = (const float*)d_in[13];
  const float* bz       = (const float*)d_in[14];
  const float* Wi       = (const float*)d_in[15];
  const float* bi       = (const float*)d_in[16];
  const float* hbi      = (const float*)d_in[17];
  const float* Wo       = (const float*)d_in[18];
  const float* bo       = (const float*)d_in[19];
  const float* hbo      = (const float*)d_in[20];
  float* out = (float*)d_out;

  const int N = in_sizes[0];   // 8192
  const int E = in_sizes[1];   // 131072

  char* ws = (char*)d_ws;
  const size_t MB = 1u << 20;
  float* X0   = (float*)(ws + 0 * MB);
  float* B1p  = (float*)(ws + 4 * MB);
  float* B2p  = (float*)(ws + 8 * MB);
  float* AGG  = (float*)(ws + 12 * MB);
  float* B3p  = (float*)(ws + 16 * MB);
  float* ZML  = (float*)(ws + 12 * MB);   // overlaps AGG+B3p (dead during its lifetime)
  float* G    = (float*)(ws + 20 * MB);
  int*   offp = (int*)(ws + 20 * MB + 256 * 1024);   // N+1 ints
  int*   curp = (int*)(ws + 20 * MB + 512 * 1024);   // N ints
  int*   cntp = (int*)(ws + 20 * MB + 768 * 1024);   // N ints
  int*   psrc = (int*)(ws + 21 * MB);                // E ints
  int*   pet  = (int*)(ws + 21 * MB + 512 * 1024);   // E ints
  float* pnrm = (float*)(ws + 22 * MB);              // E floats

  dim3 blk(256);

  // ---- CSR build (amortized over both RGCN layers) ----
  hipMemsetAsync(cntp, 0, (size_t)N * sizeof(int), stream);
  k_hist<<<dim3((E + 255) / 256), blk, 0, stream>>>(dst, cntp, E);
  k_scan<<<dim3(1), dim3(1024), 0, stream>>>(cntp, offp, curp, N, E);
  k_scatter<<<dim3((E + 255) / 256), blk, 0, stream>>>(src, dst, et, norm, curp,
                                                       psrc, pet, pnrm, E);

  // 1. x0
  k_gather<<<dim3((N * (Hdim / 4) + 255) / 256), blk, 0, stream>>>(emb, node_ids, X0, N);
  // 2. layer-0 edge aggregation (segment-reduce; writes all rows, no memset)
  k_edge2<<<dim3(N), dim3(128), 0, stream>>>(X0, W0, offp, psrc, pet, pnrm, AGG);
  // 3. h1 = relu(agg + b0 + x0@loop0)
  k_gemm<<<dim3(N / 64, Hdim / 64), blk, 0, stream>>>(X0, loop0, B1p, AGG, b0, nullptr, N, Hdim, 1);
  // 4. layer-1 edge aggregation
  k_edge2<<<dim3(N), dim3(128), 0, stream>>>(B1p, W1, offp, psrc, pet, pnrm, AGG);
  // 5. h2 = agg + b1 + h1@loop1
  k_gemm<<<dim3(N / 64, Hdim / 64), blk, 0, stream>>>(B1p, loop1, B2p, AGG, b1, nullptr, N, Hdim, 0);
  // 6. zml = h2@Wz + bz   [N, 256]
  k_gemm<<<dim3(N / 64, 256 / 64), blk, 0, stream>>>(B2p, Wz, ZML, nullptr, bz, nullptr, N, 256, 0);
  // 7. z = mean + exp(log_std)*eps  -> B1p
  k_z<<<dim3((N * Hdim) / 256), blk, 0, stream>>>(ZML, eps, B1p, N);
  // 8. C1 = z@Wi + bi + x0 -> B3p
  k_gemm<<<dim3(N / 64, Hdim / 64), blk, 0, stream>>>(B1p, Wi, B3p, nullptr, bi, X0, N, Hdim, 0);
  // 9. G1 = z^T @ C1
  hipMemsetAsync(G, 0, (size_t)Hdim * Hdim * sizeof(float), stream);
  k_xty<<<dim3(32, 4), blk, 0, stream>>>(B1p, B3p, G, N);
  // 10. h3 = z@G1 + hbi -> B2p
  k_gemm<<<dim3(N / 64, Hdim / 64), blk, 0, stream>>>(B1p, G, B2p, nullptr, hbi, nullptr, N, Hdim, 0);
  // 11. C2 = h3@Wo + bo + x0 -> B3p
  k_gemm<<<dim3(N / 64, Hdim / 64), blk, 0, stream>>>(B2p, Wo, B3p, nullptr, bo, X0, N, Hdim, 0);
  // 12. G2 = h3^T @ C2
  hipMemsetAsync(G, 0, (size_t)Hdim * Hdim * sizeof(float), stream);
  k_xty<<<dim3(32, 4), blk, 0, stream>>>(B2p, B3p, G, N);
  // 13. out = h3@G2 + hbo
  k_gemm<<<dim3(N / 64, Hdim / 64), blk, 0, stream>>>(B2p, G, out, nullptr, hbo, nullptr, N, Hdim, 0);
}